// Round 9
// baseline (1771.812 us; speedup 1.0000x reference)
//
#include <hip/hip_runtime.h>
#include <math.h>

// Problem constants
#define N_ROWS   16384   // B*H*W
#define N_CODES  16384   // N_EMBED
#define K_DIM    256     // EMBED_DIM
#define HW       1024    // 32*32
#define N_ELEMS  4194304 // N_ROWS * K_DIM

// Output layout (floats), concatenated in reference return order
#define OUT_ZQ      0
#define OUT_LOSS    4194304
#define OUT_PERP    4194305
#define OUT_ONEHOT  4194306
#define OUT_IDX     272629762   // 4194306 + 16384*16384

// ws layout (bytes) — small scratch only
#define WS_LOSS    0        // double
#define WS_HIST    64       // 16384 u32
#define WS_IDX     65600    // 16384 i32
#define WS_ENORM   131136   // 16384 f32
#define WS_ZNORM   196672   // 16384 f32

// Big scratch INSIDE the one-hot output region (re-poisoned every call,
// fully overwritten by onehot_fill at the end). scb = d_out+OUT_ONEHOT+8B.
#define SC_ZT    0          // 16 MB  fp32 z transposed [N_ROWS][K_DIM]
#define SC_ZHI   16777216   // 8 MB   bf16 stripe-swizzled
#define SC_EHI   33554432   // 8 MB   bf16 stripe-swizzled
#define SC_BMIN  41943040   // 8 MB   f32  [N_ROWS][128]
#define SC_BPACK 50331648   // 8 MB   u32  [N_ROWS][128] = (idx<<8)|cnt

// Filter margin (validated R7 at 4e-4): covers dropped zlo terms + bf16
// rounding + ref fp32 quant slop with >4x headroom.
#define MARGIN 4.0e-4f

typedef float  floatx2 __attribute__((ext_vector_type(2)));
typedef float  f32x4   __attribute__((ext_vector_type(4)));
typedef short  bf16x8  __attribute__((ext_vector_type(8)));
typedef unsigned short u16x8 __attribute__((ext_vector_type(8)));

__device__ __forceinline__ unsigned short bf16rn(float f) {
    unsigned int x = __float_as_uint(f);
    return (unsigned short)((x + 0x7fffu + ((x >> 16) & 1u)) >> 16);
}

// Stripe-swizzled bf16 layout (validated R5-R7): stripes of (8 rows x 64 k)
// = 1024 B; stripe id = (row>>3)*4 + (k>>6); within stripe, ushort offset =
// (row&7)*64 + ((k&63) ^ ((row&7)<<3)). Conflict-free ds_read_b128 (measured
// 0 conflicts); stripes are verbatim-copyable by global_load_lds.

// ---------------------------------------------------------------------------
// convert z: emit zt (fp32 [n][k]) + zhi (swizzled bf16)
__global__ __launch_bounds__(256) void convert_z_kernel(
    const float* __restrict__ z, float* __restrict__ zt,
    unsigned short* __restrict__ zhi)
{
    const int tid = blockIdx.x * 256 + threadIdx.x;   // 524288 total
    const int n  = tid & 16383;                       // n-fast: coalesced z
    const int kg = tid >> 14;                         // 0..31 (8 k's each)
    const int bimg = n >> 10, sp = n & 1023;
    const float* zp = z + (size_t)bimg * (K_DIM * HW) + (size_t)(kg * 8) * HW + sp;

    float f[8]; u16x8 hv;
    #pragma unroll
    for (int j = 0; j < 8; ++j) f[j] = zp[(size_t)j * HW];
    #pragma unroll
    for (int j = 0; j < 8; ++j) hv[j] = bf16rn(f[j]);

    float4 a = make_float4(f[0], f[1], f[2], f[3]);
    float4 b = make_float4(f[4], f[5], f[6], f[7]);
    *(float4*)(zt + (size_t)n * 256 + kg * 8)     = a;
    *(float4*)(zt + (size_t)n * 256 + kg * 8 + 4) = b;

    const int rs = n >> 3, rowin = n & 7, kc = kg >> 3;
    const size_t stripe = (size_t)(rs * 4 + kc) * 512;  // ushort units
    const int inoff = rowin * 64 + ((((kg & 7) * 8)) ^ (rowin << 3));
    *(u16x8*)(zhi + stripe + inoff) = hv;
}

// convert emb: ehi (swizzled bf16)
__global__ __launch_bounds__(256) void convert_e_kernel(
    const float* __restrict__ emb, unsigned short* __restrict__ ehi)
{
    const int tid = blockIdx.x * 256 + threadIdx.x;
    const int kg = tid & 31;                          // kg-fast: coalesced emb
    const int j  = tid >> 5;
    const float* ep = emb + (size_t)j * 256 + kg * 8;
    u16x8 hv;
    #pragma unroll
    for (int t = 0; t < 8; ++t) hv[t] = bf16rn(ep[t]);
    const int rs = j >> 3, rowin = j & 7, kc = kg >> 3;
    const size_t stripe = (size_t)(rs * 4 + kc) * 512;
    const int inoff = rowin * 64 + ((((kg & 7) * 8)) ^ (rowin << 3));
    *(u16x8*)(ehi + stripe + inoff) = hv;
}

// ---------------------------------------------------------------------------
// znorm/enorm: numpy-pairwise bit-match (validated round 4)
__global__ __launch_bounds__(256) void znorm_kernel(
    const float* __restrict__ z, float* __restrict__ znorm)
{
    const int n = blockIdx.x * 256 + threadIdx.x;
    const int b = n >> 10;
    const int sp = n & 1023;
    const float* zr = z + (size_t)b * K_DIM * HW + sp;

    float h0, h1;
    {
        float r[8];
        #pragma unroll
        for (int j = 0; j < 8; ++j) {
            float v = zr[(size_t)j * HW];
            float sq = v * v; asm volatile("" : "+v"(sq));
            r[j] = sq;
        }
        for (int i = 8; i < 128; i += 8) {
            #pragma unroll
            for (int j = 0; j < 8; ++j) {
                float v = zr[(size_t)(i + j) * HW];
                float sq = v * v; asm volatile("" : "+v"(sq));
                r[j] += sq;
            }
        }
        h0 = ((r[0] + r[1]) + (r[2] + r[3])) + ((r[4] + r[5]) + (r[6] + r[7]));
    }
    {
        float r[8];
        #pragma unroll
        for (int j = 0; j < 8; ++j) {
            float v = zr[(size_t)(128 + j) * HW];
            float sq = v * v; asm volatile("" : "+v"(sq));
            r[j] = sq;
        }
        for (int i = 8; i < 128; i += 8) {
            #pragma unroll
            for (int j = 0; j < 8; ++j) {
                float v = zr[(size_t)(128 + i + j) * HW];
                float sq = v * v; asm volatile("" : "+v"(sq));
                r[j] += sq;
            }
        }
        h1 = ((r[0] + r[1]) + (r[2] + r[3])) + ((r[4] + r[5]) + (r[6] + r[7]));
    }
    znorm[n] = h0 + h1;
}

__global__ __launch_bounds__(256) void enorm_kernel(
    const float* __restrict__ emb, float* __restrict__ enorm)
{
    const int jc = blockIdx.x * 256 + threadIdx.x;
    const float* er = emb + (size_t)jc * K_DIM;

    float h0, h1;
    {
        float r[8];
        #pragma unroll
        for (int j = 0; j < 8; ++j) {
            float v = er[j];
            float sq = v * v; asm volatile("" : "+v"(sq));
            r[j] = sq;
        }
        for (int i = 8; i < 128; i += 8) {
            #pragma unroll
            for (int j = 0; j < 8; ++j) {
                float v = er[i + j];
                float sq = v * v; asm volatile("" : "+v"(sq));
                r[j] += sq;
            }
        }
        h0 = ((r[0] + r[1]) + (r[2] + r[3])) + ((r[4] + r[5]) + (r[6] + r[7]));
    }
    {
        float r[8];
        #pragma unroll
        for (int j = 0; j < 8; ++j) {
            float v = er[128 + j];
            float sq = v * v; asm volatile("" : "+v"(sq));
            r[j] = sq;
        }
        for (int i = 8; i < 128; i += 8) {
            #pragma unroll
            for (int j = 0; j < 8; ++j) {
                float v = er[128 + i + j];
                float sq = v * v; asm volatile("" : "+v"(sq));
                r[j] += sq;
            }
        }
        h1 = ((r[0] + r[1]) + (r[2] + r[3])) + ((r[4] + r[5]) + (r[6] + r[7]));
    }
    enorm[jc] = h0 + h1;
}

// ---------------------------------------------------------------------------
// Phase A: pure-bf16 MFMA filter, K=256. Tile 256 rows x 128 codes, 8 waves
// (4x2). B panel resident in LDS (64KB, staged once). A fragments read
// directly from global (L2-hot), SOFTWARE-PIPELINED one K-step ahead so the
// L2 latency hides under the current step's 16 MFMAs. Zero K-loop barriers.
__global__ __launch_bounds__(512, 4) void mfma_min_kernel(
    const unsigned short* __restrict__ zhi, const unsigned short* __restrict__ ehi,
    const float* __restrict__ enorm,
    float* __restrict__ bmin, unsigned int* __restrict__ bpack)
{
    __shared__ unsigned short Bs[32768];      // 64KB (reused by epilogue)

    const int cb = blockIdx.x;    // 0..127 code block (fast: A stays L2-hot;
                                  // XCD = cb%8 -> each XCD's B set = 1MB, L2-fit)
    const int rb = blockIdx.y;    // 0..63  row tile
    const int tid = threadIdx.x;
    const int wid = tid >> 6;     // 0..7
    const int lane = tid & 63;
    const int wr = wid >> 1;      // 0..3 row quadrant (64 rows)
    const int wc = wid & 1;       // 0..1 col half (64 cols)
    const int l15 = lane & 15, l4 = lane >> 4;

    // stage B panel once: stripes cb*64.. are a contiguous 64KB in global
    {
        const unsigned short* gb = ehi + (size_t)cb * 32768 + wid * 512 + lane * 8;
        #pragma unroll
        for (int i = 0; i < 8; ++i)
            __builtin_amdgcn_global_load_lds(
                (const __attribute__((address_space(1))) void*)(gb + i * 4096),
                (__attribute__((address_space(3))) void*)(Bs + i * 4096 + wid * 512),
                16, 0, 0);
    }

    // Compact fragment addressing (ushort units); mf/nf stride = 4096.
    const int xa = (l15 & 7) << 3;
    const int srowA = ((rb * 32 + wr * 8 + (l15 >> 3)) << 11) + (l15 & 7) * 64;
    const int pe0 = srowA + ((l4 * 8) ^ xa);
    const int po0 = srowA + ((32 + l4 * 8) ^ xa);
    const int srowB = ((wc * 8 + (l15 >> 3)) << 11) + (l15 & 7) * 64;
    const int qe0 = srowB + ((l4 * 8) ^ xa);
    const int qo0 = srowB + ((32 + l4 * 8) ^ xa);

    f32x4 acc[4][4];
    #pragma unroll
    for (int mf = 0; mf < 4; ++mf)
        #pragma unroll
        for (int nf = 0; nf < 4; ++nf)
            acc[mf][nf] = (f32x4){0.f, 0.f, 0.f, 0.f};

    // preload step-0 A fragments (issue BEFORE the barrier; the barrier's
    // vmcnt drain makes them resident when compute starts)
    bf16x8 aC[4], aN[4];
    #pragma unroll
    for (int mf = 0; mf < 4; ++mf)
        aC[mf] = *(const bf16x8*)(zhi + (size_t)(pe0 + mf * 4096));

    __syncthreads();   // B panel ready

    // 8 K-steps of 32: step s -> chunk t=s>>1, parity p=s&1
    #pragma unroll
    for (int s = 0; s < 8; ++s) {
        if (s < 7) {   // prefetch next step's A (hides L2 latency under MFMAs)
            const int d1 = ((s + 1) >> 1) * 512;
            const int b0 = (((s + 1) & 1) ? po0 : pe0) + d1;
            #pragma unroll
            for (int mf = 0; mf < 4; ++mf)
                aN[mf] = *(const bf16x8*)(zhi + (size_t)(b0 + mf * 4096));
        }
        const int d = (s >> 1) * 512;
        const int q0 = ((s & 1) ? qo0 : qe0) + d;
        #pragma unroll
        for (int nf = 0; nf < 4; ++nf) {
            const bf16x8 b = *(const bf16x8*)(Bs + q0 + nf * 4096);
            #pragma unroll
            for (int mf = 0; mf < 4; ++mf)
                acc[mf][nf] = __builtin_amdgcn_mfma_f32_16x16x32_bf16(
                    aC[mf], b, acc[mf][nf], 0, 0, 0);
        }
        #pragma unroll
        for (int mf = 0; mf < 4; ++mf) aC[mf] = aN[mf];
    }
    __syncthreads();   // all B reads done before LDS reuse

    // ---- epilogue: s~ = enorm - 2*acc; per (row, col-block) {min, argmin,
    // count within MARGIN of BLOCK min} (validated R6/R7) ----
    float en[4];
    #pragma unroll
    for (int nf = 0; nf < 4; ++nf)
        en[nf] = enorm[cb * 128 + wc * 64 + nf * 16 + l15];

    float*        Vh = (float*)&Bs[0];             // [2][256]
    unsigned int* Ih = (unsigned int*)(Vh + 512);  // [2][256]
    unsigned int* Ch = (unsigned int*)(Ih + 512);  // [2][256]
    float*        Gm = (float*)(Ch + 512);         // [256]

    #pragma unroll
    for (int mf = 0; mf < 4; ++mf) {
        #pragma unroll
        for (int i = 0; i < 4; ++i) {
            float bv = 3.4e38f; int bc = 0x7fffffff;
            #pragma unroll
            for (int nf = 0; nf < 4; ++nf) {
                const float s = en[nf] - 2.0f * acc[mf][nf][i];
                const int col = cb * 128 + wc * 64 + nf * 16 + l15;
                if (s < bv) { bv = s; bc = col; }   // ascending cols per lane
            }
            #pragma unroll
            for (int off = 1; off < 16; off <<= 1) {
                const float ov = __shfl_xor(bv, off);
                const int oc = __shfl_xor(bc, off);
                if (ov < bv || (ov == bv && oc < bc)) { bv = ov; bc = oc; }
            }
            if (l15 == 0) {
                const int rr = wr * 64 + mf * 16 + l4 * 4 + i;
                Vh[wc * 256 + rr] = bv;
                Ih[wc * 256 + rr] = (unsigned int)bc;
            }
        }
    }
    __syncthreads();
    if (tid < 256) {
        const float v0 = Vh[tid], v1 = Vh[256 + tid];
        const unsigned int i0 = Ih[tid], i1 = Ih[256 + tid];
        float v; unsigned int ix;
        if (v1 < v0 || (v1 == v0 && i1 < i0)) { v = v1; ix = i1; }
        else { v = v0; ix = i0; }
        Gm[tid] = v;
        Vh[tid] = v;
        Ih[tid] = ix;
    }
    __syncthreads();
    #pragma unroll
    for (int mf = 0; mf < 4; ++mf) {
        #pragma unroll
        for (int i = 0; i < 4; ++i) {
            const int rr = wr * 64 + mf * 16 + l4 * 4 + i;
            const float thr = Gm[rr] + MARGIN;
            int cnt = 0;
            #pragma unroll
            for (int nf = 0; nf < 4; ++nf)
                cnt += (en[nf] - 2.0f * acc[mf][nf][i] <= thr) ? 1 : 0;
            #pragma unroll
            for (int off = 1; off < 16; off <<= 1) cnt += __shfl_xor(cnt, off);
            if (l15 == 0) Ch[wc * 256 + rr] = (unsigned int)cnt;
        }
    }
    __syncthreads();
    if (tid < 256) {
        unsigned int cnt = Ch[tid] + Ch[256 + tid];
        const size_t o = (size_t)(rb * 256 + tid) * 128 + cb;
        bmin[o] = Vh[tid];
        bpack[o] = (Ih[tid] << 8) | (cnt > 255u ? 255u : cnt);
    }
}

// ---------------------------------------------------------------------------
// Phase B: wave per row; exact rescoring of candidates (bitwise reference
// argmin incl. ties; validated R4-R7).
__global__ __launch_bounds__(256) void argmin_exact_kernel(
    const float* __restrict__ zt, const float* __restrict__ emb,
    const float* __restrict__ enorm, const float* __restrict__ znorm,
    const float* __restrict__ bmin, const unsigned int* __restrict__ bpack,
    int* __restrict__ idx_ws, float* __restrict__ out_idx,
    unsigned int* __restrict__ hist)
{
    __shared__ float ZL[4][256];
    const int tid = threadIdx.x, wv = tid >> 6, lane = tid & 63;
    const int n = blockIdx.x * 4 + wv;

    *(float4*)&ZL[wv][lane * 4] = ((const float4*)(zt + (size_t)n * 256))[lane];
    __syncthreads();

    const float zn = znorm[n];
    float bd = 3.4e38f; int bi = 0x7fffffff;

    const float m0 = bmin[(size_t)n * 128 + lane];
    const float m1 = bmin[(size_t)n * 128 + 64 + lane];
    float g = fminf(m0, m1);
    #pragma unroll
    for (int off = 1; off < 64; off <<= 1) g = fminf(g, __shfl_xor(g, off));
    const float thr = g + MARGIN;

    #pragma unroll
    for (int half = 0; half < 2; ++half) {
        const float bm = half ? m1 : m0;
        const unsigned int pk = bpack[(size_t)n * 128 + half * 64 + lane];
        const int cnt = (int)(pk & 255u);
        const int cand = (int)(pk >> 8);
        const bool act = (bm <= thr);
        if (act && cnt == 1) {
            const float* er = emb + (size_t)cand * 256;
            float dot = 0.f;
            for (int k = 0; k < 256; ++k) dot += ZL[wv][k] * er[k];
            const float t1 = zn + enorm[cand];
            const float d = t1 - 2.0f * dot;
            if (d < bd || (d == bd && cand < bi)) { bd = d; bi = cand; }
        }
        unsigned long long need = __ballot(act && cnt > 1);
        while (need) {
            const int c2 = __ffsll((unsigned long long)need) - 1;
            need &= need - 1;
            const int base = (half * 64 + c2) * 128;
            #pragma unroll
            for (int t = 0; t < 2; ++t) {
                const int j = base + t * 64 + lane;
                const float* er = emb + (size_t)j * 256;
                float dot = 0.f;
                for (int k = 0; k < 256; ++k) dot += ZL[wv][k] * er[k];
                const float t1 = zn + enorm[j];
                const float d = t1 - 2.0f * dot;
                if (d < bd || (d == bd && j < bi)) { bd = d; bi = j; }
            }
        }
    }
    #pragma unroll
    for (int off = 1; off < 64; off <<= 1) {
        const float od = __shfl_xor(bd, off);
        const int oi = __shfl_xor(bi, off);
        if (od < bd || (od == bd && oi < bi)) { bd = od; bi = oi; }
    }
    if (lane == 0) {
        idx_ws[n] = bi;
        out_idx[n] = (float)bi;
        atomicAdd(&hist[bi], 1u);
    }
}

// ---------------------------------------------------------------------------
// z_q gather + fused squared-error sum. 1024-thr blocks (16 waves) for 4x
// the TLP on the LLC gather of emb rows.
__global__ __launch_bounds__(1024) void gather_zq_loss_kernel(
    const float* __restrict__ z, const float* __restrict__ emb,
    const int* __restrict__ idx_ws, float* __restrict__ zq_out,
    double* __restrict__ loss_accum)
{
    const int g = blockIdx.x;
    const int wave = threadIdx.x >> 6;   // 0..15
    const int lane = threadIdx.x & 63;
    const int n = g * 64 + lane;
    const int b = n >> 10;
    const int sp = n & 1023;
    const int code = idx_ws[n];
    const float* erow = emb + (size_t)code * K_DIM;
    const float* zrow = z + (size_t)b * K_DIM * HW + sp;
    float* orow = zq_out + (size_t)b * K_DIM * HW + sp;

    float lsum = 0.0f;
    for (int c = wave; c < K_DIM; c += 16) {
        const float e  = erow[c];
        const float zp = zrow[(size_t)c * HW];
        orow[(size_t)c * HW] = e;
        const float d = e - zp;
        lsum += d * d;
    }
    #pragma unroll
    for (int off = 32; off; off >>= 1) lsum += __shfl_xor(lsum, off);
    __shared__ float wsum[16];
    if (lane == 0) wsum[wave] = lsum;
    __syncthreads();
    if (threadIdx.x == 0) {
        float s = 0.f;
        #pragma unroll
        for (int w = 0; w < 16; ++w) s += wsum[w];
        atomicAdd(loss_accum, (double)s);
    }
}

// ---------------------------------------------------------------------------
// one-hot fill: head float2, float4 body, tail float2; nontemporal stores
// (write-once 1.07 GB). Also overwrites all scratch in the output region.
__global__ __launch_bounds__(256) void onehot_fill_kernel(
    const int* __restrict__ idx_ws, float* __restrict__ out)  // +OUT_ONEHOT
{
    const int r = blockIdx.x;
    const int code = idx_ws[r];
    float* row = out + (size_t)r * 16384;
    for (int s = threadIdx.x; s < 4096; s += 256) {
        if (s == 0) {
            floatx2 h = {code == 0 ? 1.f : 0.f, code == 1 ? 1.f : 0.f};
            __builtin_nontemporal_store(h, (floatx2*)row);
        }
        if (s < 4095) {
            const int cc = 2 + s * 4;
            f32x4 v = {code == cc ? 1.f : 0.f, code == cc + 1 ? 1.f : 0.f,
                       code == cc + 2 ? 1.f : 0.f, code == cc + 3 ? 1.f : 0.f};
            __builtin_nontemporal_store(v, (f32x4*)(row + cc));
        } else {
            floatx2 tpair = {code == 16382 ? 1.f : 0.f, code == 16383 ? 1.f : 0.f};
            __builtin_nontemporal_store(tpair, (floatx2*)(row + 16382));
        }
    }
}

// ---------------------------------------------------------------------------
__global__ __launch_bounds__(1024) void finalize_scalars_kernel(
    const double* __restrict__ loss_accum, const unsigned int* __restrict__ hist,
    float* __restrict__ out_scalars)
{
    const int tid = threadIdx.x;
    double s = 0.0;
    for (int j = tid; j < N_CODES; j += 1024) {
        const double p = (double)hist[j] * (1.0 / (double)N_ROWS);
        s += p * log(p + 1e-10);
    }
    #pragma unroll
    for (int off = 32; off; off >>= 1) s += __shfl_xor(s, off);
    __shared__ double sh[16];
    const int wave = tid >> 6, lane = tid & 63;
    if (lane == 0) sh[wave] = s;
    __syncthreads();
    if (tid == 0) {
        double S = 0.0;
        for (int w = 0; w < 16; ++w) S += sh[w];
        out_scalars[0] = (float)(1.25 * loss_accum[0] * (1.0 / (double)N_ELEMS));
        out_scalars[1] = (float)exp(-S);
    }
}

// ---------------------------------------------------------------------------
extern "C" void kernel_launch(void* const* d_in, const int* in_sizes, int n_in,
                              void* d_out, int out_size, void* d_ws, size_t ws_size,
                              hipStream_t stream)
{
    const float* z   = (const float*)d_in[0];
    const float* emb = (const float*)d_in[1];
    float* out = (float*)d_out;
    char* ws = (char*)d_ws;

    double*       loss_accum = (double*)(ws + WS_LOSS);
    unsigned int* hist       = (unsigned int*)(ws + WS_HIST);
    int*          idx_ws     = (int*)(ws + WS_IDX);
    float*        enorm      = (float*)(ws + WS_ENORM);
    float*        znorm      = (float*)(ws + WS_ZNORM);

    char* scb = (char*)(out + OUT_ONEHOT) + 8;   // 16B-aligned scratch base
    float*          zt    = (float*)(scb + SC_ZT);
    unsigned short* zhi   = (unsigned short*)(scb + SC_ZHI);
    unsigned short* ehi   = (unsigned short*)(scb + SC_EHI);
    float*          bminp = (float*)(scb + SC_BMIN);
    unsigned int*   bpack = (unsigned int*)(scb + SC_BPACK);

    (void)hipMemsetAsync(ws, 0, WS_ENORM, stream);   // loss + hist (+idx)

    convert_z_kernel<<<dim3(2048), dim3(256), 0, stream>>>(z, zt, zhi);
    convert_e_kernel<<<dim3(2048), dim3(256), 0, stream>>>(emb, ehi);
    znorm_kernel<<<dim3(N_ROWS / 256), dim3(256), 0, stream>>>(z, znorm);
    enorm_kernel<<<dim3(N_CODES / 256), dim3(256), 0, stream>>>(emb, enorm);

    // grid: cb fastest so co-resident blocks share A slices (L2-hot zhi)
    mfma_min_kernel<<<dim3(128, 64), dim3(512), 0, stream>>>(
        zhi, ehi, enorm, bminp, bpack);

    argmin_exact_kernel<<<dim3(N_ROWS / 4), dim3(256), 0, stream>>>(
        zt, emb, enorm, znorm, bminp, bpack, idx_ws, out + OUT_IDX, hist);

    gather_zq_loss_kernel<<<dim3(N_ROWS / 64), dim3(1024), 0, stream>>>(
        z, emb, idx_ws, out + OUT_ZQ, loss_accum);

    onehot_fill_kernel<<<dim3(16384), dim3(256), 0, stream>>>(
        idx_ws, out + OUT_ONEHOT);

    finalize_scalars_kernel<<<dim3(1), dim3(1024), 0, stream>>>(
        loss_accum, hist, out + OUT_LOSS);
}